// Round 19
// baseline (148.436 us; speedup 1.0000x reference)
//
#include <hip/hip_runtime.h>
#include <stdint.h>

typedef _Float16 f16;
typedef __attribute__((ext_vector_type(8))) _Float16 f16x8;
typedef __attribute__((ext_vector_type(4))) _Float16 f16x4;
typedef __attribute__((ext_vector_type(2))) __fp16 fp16x2;
typedef __attribute__((ext_vector_type(4))) float f32x4;

#define HD 1024
#define NH 16
#define DH 64
#define BB 2
#define MM 2048
#define BH (BB*NH)          // 32
#define MT (BB*MM)          // 4096 total rows

__device__ __forceinline__ void gl_lds16(const f16* g, f16* l) {
    __builtin_amdgcn_global_load_lds((const __attribute__((address_space(1))) uint32_t*)g,
                                     (__attribute__((address_space(3))) uint32_t*)l, 16, 0, 0);
}

__device__ __forceinline__ float fexp2(float x) {
    float r; asm("v_exp_f32 %0, %1" : "=v"(r) : "v"(x)); return r;
}

// ---------------- fused fp32 -> fp16 conversion (x + 4 weights, contiguous dst) ----------------
__global__ void cvt_all(const float* __restrict__ x,  const float* __restrict__ wq,
                        const float* __restrict__ wk, const float* __restrict__ wv,
                        const float* __restrict__ wo, f16* __restrict__ dst) {
    const int XN4 = MT * HD / 4;          // 1048576
    const int WN4 = HD * HD / 4;          // 262144 = 2^18
    int i = blockIdx.x * blockDim.x + threadIdx.x;
    if (i >= XN4 + 4 * WN4) return;
    const float* s; int off;
    if (i < XN4) { s = x; off = i; }
    else {
        int k = i - XN4, wsel = k >> 18;
        off = k & (WN4 - 1);
        s = wsel == 0 ? wq : wsel == 1 ? wk : wsel == 2 ? wv : wo;
    }
    float4 v = ((const float4*)s)[off];
    f16x4 h;
    h[0] = (f16)v.x; h[1] = (f16)v.y; h[2] = (f16)v.z; h[3] = (f16)v.w;
    ((f16x4*)dst)[i] = h;
}

// ---------------- m97-style GEMM (R18 form, unchanged) ------------------------------------------
// MODE 0: fused QKV, 128x128 tile, grid=768. W = [3072][1024]. Q scaled by (1/8)*log2(e); V^T out.
// MODE 1: out proj, 128x64 tile, grid=512. fp32 out = acc + b0.
template<int MODE>
__global__ __launch_bounds__(256, 3) void gemm_m97(const f16* __restrict__ A,
                                                   const f16* __restrict__ W,
                                                   const float* __restrict__ b0,
                                                   const float* __restrict__ b1,
                                                   const float* __restrict__ b2,
                                                   f16* __restrict__ oh,
                                                   float* __restrict__ of) {
    constexpr int BN = (MODE == 0) ? 128 : 64;   // tile N
    constexpr int NJ = BN / 32;                  // bf frags per wave (4 or 2)
    __shared__ f16 As[128 * 32];
    __shared__ f16 Bs[BN * 32];
    const int bid = blockIdx.x;
    int bn, bm;
    { int xcd = bid & 7, r = bid >> 3;
      bn = (MODE == 0) ? xcd * 3 + (r >> 5) : xcd * 2 + (r >> 5);
      bm = r & 31; }
    const int t = threadIdx.x, w = t >> 6, lane = t & 63;
    const int wr = w >> 1, wc = w & 1, lr = lane & 15, lg = lane >> 4;
    f32x4 acc[4][NJ] = {};

    const int srow = w * 16 + (lane >> 2);
    const int schunk = lane & 3;
    const f16* Ab = A + (size_t)(bm * 128) * HD;
    const f16* Wb = W + (size_t)(bn * BN) * HD;
    f16* Asw = As + w * 512;
    f16* Bsw = Bs + w * 512;

#define GSTAGE(K0)                                                              \
    {                                                                           \
        _Pragma("unroll")                                                       \
        for (int i = 0; i < 2; i++) {                                           \
            int r = i * 64 + srow;                                              \
            int gc = ((schunk ^ ((r >> 1) & 3)) * 8);                           \
            gl_lds16(Ab + (size_t)r * HD + (K0) + gc, Asw + i * 2048);          \
        }                                                                       \
        if (MODE == 0) {                                                        \
            _Pragma("unroll")                                                   \
            for (int i = 0; i < 2; i++) {                                       \
                int r = i * 64 + srow;                                          \
                int gc = ((schunk ^ ((r >> 1) & 3)) * 8);                       \
                gl_lds16(Wb + (size_t)r * HD + (K0) + gc, Bsw + i * 2048);      \
            }                                                                   \
        } else {                                                                \
            int r = srow;                                                       \
            int gc = ((schunk ^ ((r >> 1) & 3)) * 8);                           \
            gl_lds16(Wb + (size_t)r * HD + (K0) + gc, Bsw);                     \
        }                                                                       \
    }

    GSTAGE(0)

    for (int k0 = 0;;) {
        __syncthreads();
        f16x8 af[4], bf[NJ];
        #pragma unroll
        for (int i = 0; i < 4; i++) {
            int ra = wr * 64 + i * 16 + lr;
            af[i] = *(const f16x8*)(As + ra * 32 + ((lg ^ ((ra >> 1) & 3)) * 8));
        }
        #pragma unroll
        for (int j = 0; j < NJ; j++) {
            int rb = wc * (BN / 2) + j * 16 + lr;
            bf[j] = *(const f16x8*)(Bs + rb * 32 + ((lg ^ ((rb >> 1) & 3)) * 8));
        }
        #pragma unroll
        for (int i = 0; i < 4; i++)
            #pragma unroll
            for (int j = 0; j < NJ; j++)
                acc[i][j] = __builtin_amdgcn_mfma_f32_16x16x32_f16(af[i], bf[j], acc[i][j], 0, 0, 0);
        k0 += 32;
        if (k0 >= HD) break;
        __syncthreads();
        GSTAGE(k0)
    }
#undef GSTAGE

    if (MODE == 0) {
        const int mat = bn >> 3;             // 0=Q 1=K 2=V
        const float* bp = mat == 0 ? b0 : mat == 1 ? b1 : b2;
        f16* base = oh + (size_t)mat * BH * MM * DH;
        #pragma unroll
        for (int i = 0; i < 4; i++) {
            #pragma unroll
            for (int j = 0; j < NJ; j++) {
                int n = bn * 128 + wc * 64 + j * 16 + lr;
                int nn = n & 1023, h = nn >> 6, dh = nn & 63;
                float bvv = bp[nn];
                int mg0 = bm * 128 + wr * 64 + i * 16 + lg * 4;
                int b = mg0 >> 11, mmr0 = mg0 & 2047;
                if (mat == 2) {
                    f16x4 o;
                    #pragma unroll
                    for (int r = 0; r < 4; r++) o[r] = (f16)(acc[i][j][r] + bvv);
                    *(f16x4*)(base + ((size_t)((b * NH + h) * DH + dh)) * MM + mmr0) = o;
                } else {
                    // Q pre-scaled by (1/8)*log2(e) so softmax uses raw v_exp_f32 (2^x)
                    float sc = (mat == 0) ? 0.1803368801111204f : 1.0f;
                    #pragma unroll
                    for (int r = 0; r < 4; r++)
                        base[((size_t)((b * NH + h) * MM + mmr0 + r)) * DH + dh] =
                            (f16)((acc[i][j][r] + bvv) * sc);
                }
            }
        }
    } else {
        #pragma unroll
        for (int i = 0; i < 4; i++)
            #pragma unroll
            for (int j = 0; j < NJ; j++) {
                int n = bn * 64 + wc * 32 + j * 16 + lr;
                float bvv = b0[n];
                #pragma unroll
                for (int r = 0; r < 4; r++) {
                    int mg = bm * 128 + wr * 64 + i * 16 + lg * 4 + r;
                    of[(size_t)mg * HD + n] = acc[i][j][r] + bvv;
                }
            }
    }
}

// ---------------- flash attention: 4-buffer K/V, ONE barrier per 2 tiles (16 rendezvous) ---------
// Super-step sigma: vmcnt(0)+barrier -> stage tiles 2s+2,2s+3 -> compute body 2s -> body 2s+1.
// Barrier proves bodies 2s-2,2s-1 (previous readers of the staging targets) are done block-wide.
// Compute register footprint identical to R14 (one tile at a time). LDS 32+32+16=80KB, 2 blk/CU.
// Fixed-base softmax (scores bounded; diag score=0 -> P=1). Q pre-scaled by log2e/8.
__global__ __launch_bounds__(512, 4) void attn_kernel(const f16* __restrict__ Q,
                                                      const f16* __restrict__ K,
                                                      const f16* __restrict__ Vt,
                                                      f16* __restrict__ ctx) {
    __shared__ f16 Kl[4][64][64];   // 32 KB: [buf][kv][dh], 16B chunks XOR-swizzled by row&7
    __shared__ f16 Vl[4][64][64];   // 32 KB: [buf][dh][kv]
    __shared__ f16 Pl[8][32][32];   // 16 KB: per-wave P, granule-XOR by (row>>1)&3
    const int bid = blockIdx.x;                  // [0,512)
    const int xcd = bid & 7, idx = bid >> 3;     // idx in [0,64)
    const int bh = xcd * 4 + (idx >> 4);         // 4 heads per XCD
    const int qblk2 = idx & 15;                  // 128-row q block

    const int t = threadIdx.x, w = t >> 6, lane = t & 63;
    const int lr = lane & 15, lg = lane >> 4;
    const int wq = w >> 1, wkv = w & 1;          // 4 x 2 quadrant role
    const int q0B = qblk2 * 128 + wq * 32;
    const int kvb = wkv * 32;
    const int dtile = q0B >> 6;                  // KV tile containing this wave's diagonal
    const bool dwave = (wkv == (wq & 1));        // wave sees the diagonal in that tile

    const f16* Qb = Q + (size_t)bh * MM * DH;
    const f16* Kb = K + (size_t)bh * MM * DH;
    const f16* Vb = Vt + (size_t)bh * DH * MM;

    const int srowS = lane >> 3;                 // 0..7 staging row-in-8
    const int sxc = ((lane & 7) ^ srowS) * 8;    // inverse-swizzled source chunk (f16 units)
    const int lds_r = w * 8;                     // wave's staging row block (8 rows)

    f16x8 qfr[2][2];
    #pragma unroll
    for (int qf = 0; qf < 2; qf++)
        #pragma unroll
        for (int c = 0; c < 2; c++)
            qfr[qf][c] = *(const f16x8*)(Qb + (size_t)(q0B + qf * 16 + lr) * DH + c * 32 + lg * 8);

    f32x4 po[4][2] = {};                         // [df][qf]
    float lsum0 = 0.f, lsum1 = 0.f;
    const int sw = (lr & 7) * 8;
    const int ko0 = (lg * 8) ^ sw, ko1 = (32 + lg * 8) ^ sw;
    const int vko = (kvb + lg * 8) ^ sw;
    const int ps = (lr >> 1) & 3;
    f16* Pw = &Pl[w][0][0];
    const int pro = lr * 32 + ((lg ^ ps) * 8);

    // prologue: stage tiles 0,1 into bufs 0,1
    #pragma unroll
    for (int tt = 0; tt < 2; tt++) {
        int row = lds_r + srowS;
        gl_lds16(Kb + (size_t)(tt * 64 + row) * DH + sxc, &Kl[tt][lds_r][0]);
        gl_lds16(Vb + (size_t)row * MM + tt * 64 + sxc, &Vl[tt][lds_r][0]);
    }

// compute one tile body (no barrier/stage/vmcnt inside)
#define ACOMP(CUR, IT)                                                                       \
    {                                                                                        \
        const int it_ = (IT);                                                                \
        f32x4 s00 = {}, s01 = {}, s10 = {}, s11 = {};   /* s{fq}{qf} */                      \
        __builtin_amdgcn_s_setprio(1);                                                       \
        {                                                                                    \
            const f16* kr0 = &Kl[CUR][kvb + lr][0];                                          \
            f16x8 ka = *(const f16x8*)(kr0 + ko0);                                           \
            f16x8 kb = *(const f16x8*)(kr0 + ko1);                                           \
            s00 = __builtin_amdgcn_mfma_f32_16x16x32_f16(ka, qfr[0][0], s00, 0, 0, 0);       \
            s00 = __builtin_amdgcn_mfma_f32_16x16x32_f16(kb, qfr[0][1], s00, 0, 0, 0);       \
            s01 = __builtin_amdgcn_mfma_f32_16x16x32_f16(ka, qfr[1][0], s01, 0, 0, 0);       \
            s01 = __builtin_amdgcn_mfma_f32_16x16x32_f16(kb, qfr[1][1], s01, 0, 0, 0);       \
            const f16* kr1 = &Kl[CUR][kvb + 16 + lr][0];                                     \
            f16x8 kc = *(const f16x8*)(kr1 + ko0);                                           \
            f16x8 kd = *(const f16x8*)(kr1 + ko1);                                           \
            s10 = __builtin_amdgcn_mfma_f32_16x16x32_f16(kc, qfr[0][0], s10, 0, 0, 0);       \
            s10 = __builtin_amdgcn_mfma_f32_16x16x32_f16(kd, qfr[0][1], s10, 0, 0, 0);       \
            s11 = __builtin_amdgcn_mfma_f32_16x16x32_f16(kc, qfr[1][0], s11, 0, 0, 0);       \
            s11 = __builtin_amdgcn_mfma_f32_16x16x32_f16(kd, qfr[1][1], s11, 0, 0, 0);       \
        }                                                                                    \
        __builtin_amdgcn_s_setprio(0);                                                       \
        if (it_ == dtile && dwave) {   /* multiplicative diag-zero: score 0 -> P = 1 */      \
            int rr = lr - lg * 4;                                                            \
            if (rr >= 0 && rr < 4) { s00[rr] = 0.f; s11[rr] = 0.f; }                         \
        }                                                                                    \
        _Pragma("unroll")                                                                    \
        for (int u = 0; u < 4; u++) {                                                        \
            const f32x4 sv = (u == 0) ? s00 : (u == 1) ? s01 : (u == 2) ? s10 : s11;         \
            const int fq = u >> 1, qf = u & 1;                                               \
            float p0 = fexp2(sv[0]), p1 = fexp2(sv[1]);                                      \
            float p2 = fexp2(sv[2]), p3 = fexp2(sv[3]);                                      \
            if (qf == 0) lsum0 += (p0 + p1) + (p2 + p3);                                     \
            else         lsum1 += (p0 + p1) + (p2 + p3);                                     \
            fp16x2 lo = __builtin_amdgcn_cvt_pkrtz(p0, p1);                                  \
            fp16x2 hi = __builtin_amdgcn_cvt_pkrtz(p2, p3);                                  \
            uint2 pr; pr.x = __builtin_bit_cast(uint32_t, lo);                               \
            pr.y = __builtin_bit_cast(uint32_t, hi);                                         \
            *(f16x4*)(Pw + (qf * 16 + lr) * 32 +                                             \
                      (((fq * 2 + (lg >> 1)) ^ ps) * 8) + (lg & 1) * 4) =                    \
                __builtin_bit_cast(f16x4, pr);                                               \
        }                                                                                    \
        asm volatile("s_waitcnt lgkmcnt(0)" ::: "memory");  /* wave-local P visibility */    \
        f16x8 pf0 = *(const f16x8*)(Pw + pro);                                               \
        f16x8 pf1 = *(const f16x8*)(Pw + 512 + pro);                                         \
        __builtin_amdgcn_s_setprio(1);                                                       \
        _Pragma("unroll")                                                                    \
        for (int df = 0; df < 4; df++) {                                                     \
            const f16* vr = &Vl[CUR][df * 16 + lr][0];                                       \
            f16x8 va = *(const f16x8*)(vr + vko);                                            \
            po[df][0] = __builtin_amdgcn_mfma_f32_16x16x32_f16(va, pf0, po[df][0], 0, 0, 0); \
            po[df][1] = __builtin_amdgcn_mfma_f32_16x16x32_f16(va, pf1, po[df][1], 0, 0, 0); \
        }                                                                                    \
        __builtin_amdgcn_s_setprio(0);                                                       \
    }

// super-step: tiles T0,T0+1 from bufs BA,BB_; stage tiles T0+2,T0+3 into bufs SA,SB
#define ASUPER(BA, BB_, SA, SB, T0, DOSTG)                                                   \
    {                                                                                        \
        asm volatile("s_waitcnt vmcnt(0)" ::: "memory");  /* tiles T0,T0+1 staged (own) */   \
        __builtin_amdgcn_s_barrier();                     /* ...all waves; prev readers done */ \
        if (DOSTG) {                                                                         \
            const int ja = ((T0) + 2) * 64, jb = ((T0) + 3) * 64;                            \
            int row = lds_r + srowS;                                                         \
            gl_lds16(Kb + (size_t)(ja + row) * DH + sxc, &Kl[SA][lds_r][0]);                 \
            gl_lds16(Vb + (size_t)row * MM + ja + sxc, &Vl[SA][lds_r][0]);                   \
            gl_lds16(Kb + (size_t)(jb + row) * DH + sxc, &Kl[SB][lds_r][0]);                 \
            gl_lds16(Vb + (size_t)row * MM + jb + sxc, &Vl[SB][lds_r][0]);                   \
        }                                                                                    \
        ACOMP(BA, (T0))                                                                      \
        ACOMP(BB_, (T0) + 1)                                                                 \
    }

    for (int sp = 0; sp < 8; ++sp) {
        ASUPER(0, 1, 2, 3, 4 * sp, 1)
        ASUPER(2, 3, 0, 1, 4 * sp + 2, (sp < 7))
    }
#undef ASUPER
#undef ACOMP

    // ---- epilogue: sum lg-groups in-wave, then combine kv-halves (wave pairs w, w^1) ----
    lsum0 += __shfl_xor(lsum0, 16); lsum0 += __shfl_xor(lsum0, 32);
    lsum1 += __shfl_xor(lsum1, 16); lsum1 += __shfl_xor(lsum1, 32);
    __syncthreads();                             // Kl/Vl/Pl free for reuse
    float* shf0 = (float*)(&Kl[0][0][0]);        // qf=0 exchange: 256 rows x stride 17 f32
    float* shf1 = (float*)(&Vl[0][0][0]);        // qf=1 exchange
    float* shl  = (float*)(&Pl[0][0][0]);        // lsum exchange: 256 x 2 f32
    const int xi = wq * 64 + lane;               // [0,256)
    if (wkv == 1) {
        float* d0 = shf0 + (size_t)xi * 17;
        float* d1 = shf1 + (size_t)xi * 17;
        #pragma unroll
        for (int df = 0; df < 4; df++) {
            *(f32x4*)(d0 + df * 4) = po[df][0];
            *(f32x4*)(d1 + df * 4) = po[df][1];
        }
        shl[xi * 2]     = lsum0;
        shl[xi * 2 + 1] = lsum1;
    }
    __syncthreads();
    if (wkv == 0) {
        const float* s0 = shf0 + (size_t)xi * 17;
        const float* s1 = shf1 + (size_t)xi * 17;
        const float inv0 = 1.f / (lsum0 + shl[xi * 2]);
        const float inv1 = 1.f / (lsum1 + shl[xi * 2 + 1]);
        const int b = bh >> 4, hh = bh & 15;
        #pragma unroll
        for (int qf = 0; qf < 2; qf++) {
            const float inv = qf ? inv1 : inv0;
            const float* s = qf ? s1 : s0;
            f16* cp = ctx + ((size_t)(b * MM + q0B + qf * 16 + lr)) * HD + hh * DH;
            #pragma unroll
            for (int df = 0; df < 4; df++) {
                f16x4 o;
                #pragma unroll
                for (int r = 0; r < 4; r++)
                    o[r] = (f16)((po[df][qf][r] + s[df * 4 + r]) * inv);
                *(f16x4*)(cp + df * 16 + lg * 4) = o;
            }
        }
    }
}

extern "C" void kernel_launch(void* const* d_in, const int* in_sizes, int n_in,
                              void* d_out, int out_size, void* d_ws, size_t ws_size,
                              hipStream_t stream) {
    const float* x  = (const float*)d_in[0];
    const float* Wq = (const float*)d_in[1];
    const float* bq = (const float*)d_in[2];
    const float* Wk = (const float*)d_in[3];
    const float* bk = (const float*)d_in[4];
    const float* Wv = (const float*)d_in[5];
    const float* bv = (const float*)d_in[6];
    const float* Wo = (const float*)d_in[7];
    const float* bo = (const float*)d_in[8];
    float* out = (float*)d_out;

    f16* xh  = (f16*)d_ws;                       // 4096*1024
    f16* wqh = xh  + (size_t)MT * HD;            // 3x 1024*1024 contiguous (fused QKV weight)
    f16* woh = wqh + (size_t)3 * HD * HD;
    f16* Qh  = woh + (size_t)HD * HD;            // Qh|Kh|Vth contiguous
    f16* ctxh= Qh  + (size_t)3 * BH * MM * DH;

    const int total4 = MT * HD / 4 + HD * HD;
    cvt_all<<<(total4 + 255) / 256, 256, 0, stream>>>(x, Wq, Wk, Wv, Wo, xh);

    gemm_m97<0><<<768, 256, 0, stream>>>(xh, wqh, bq, bk, bv, Qh, nullptr);

    attn_kernel<<<512, 512, 0, stream>>>(Qh, Qh + (size_t)BH * MM * DH,
                                         Qh + (size_t)2 * BH * MM * DH, ctxh);

    gemm_m97<1><<<512, 256, 0, stream>>>(ctxh, woh, bo, nullptr, nullptr, nullptr, out);
}

// Round 20
// 115.306 us; speedup vs baseline: 1.2873x; 1.2873x over previous
//
#include <hip/hip_runtime.h>
#include <stdint.h>

typedef _Float16 f16;
typedef __attribute__((ext_vector_type(8))) _Float16 f16x8;
typedef __attribute__((ext_vector_type(4))) _Float16 f16x4;
typedef __attribute__((ext_vector_type(2))) __fp16 fp16x2;
typedef __attribute__((ext_vector_type(4))) float f32x4;

#define HD 1024
#define NH 16
#define DH 64
#define BB 2
#define MM 2048
#define BH (BB*NH)          // 32
#define MT (BB*MM)          // 4096 total rows

__device__ __forceinline__ void gl_lds16(const f16* g, f16* l) {
    __builtin_amdgcn_global_load_lds((const __attribute__((address_space(1))) uint32_t*)g,
                                     (__attribute__((address_space(3))) uint32_t*)l, 16, 0, 0);
}

__device__ __forceinline__ float fexp2(float x) {
    float r; asm("v_exp_f32 %0, %1" : "=v"(r) : "v"(x)); return r;
}

// ---------------- fused fp32 -> fp16 conversion (x + 4 weights, contiguous dst) ----------------
__global__ void cvt_all(const float* __restrict__ x,  const float* __restrict__ wq,
                        const float* __restrict__ wk, const float* __restrict__ wv,
                        const float* __restrict__ wo, f16* __restrict__ dst) {
    const int XN4 = MT * HD / 4;          // 1048576
    const int WN4 = HD * HD / 4;          // 262144 = 2^18
    int i = blockIdx.x * blockDim.x + threadIdx.x;
    if (i >= XN4 + 4 * WN4) return;
    const float* s; int off;
    if (i < XN4) { s = x; off = i; }
    else {
        int k = i - XN4, wsel = k >> 18;
        off = k & (WN4 - 1);
        s = wsel == 0 ? wq : wsel == 1 ? wk : wsel == 2 ? wv : wo;
    }
    float4 v = ((const float4*)s)[off];
    f16x4 h;
    h[0] = (f16)v.x; h[1] = (f16)v.y; h[2] = (f16)v.z; h[3] = (f16)v.w;
    ((f16x4*)dst)[i] = h;
}

// ---------------- m97-style GEMM (single buffer) ------------------------------------------------
// MODE 0: fused QKV, 128x128 tile, grid=768. W = [3072][1024]. Q scaled by (1/8)*log2(e); V^T out.
// MODE 1: out proj, 128x64 tile, grid=512 (2 blocks/CU for latency hiding). fp32 out = acc + b0.
template<int MODE>
__global__ __launch_bounds__(256, 3) void gemm_m97(const f16* __restrict__ A,
                                                   const f16* __restrict__ W,
                                                   const float* __restrict__ b0,
                                                   const float* __restrict__ b1,
                                                   const float* __restrict__ b2,
                                                   f16* __restrict__ oh,
                                                   float* __restrict__ of) {
    constexpr int BN = (MODE == 0) ? 128 : 64;   // tile N
    constexpr int NJ = BN / 32;                  // bf frags per wave (4 or 2)
    __shared__ f16 As[128 * 32];
    __shared__ f16 Bs[BN * 32];
    const int bid = blockIdx.x;
    int bn, bm;
    { int xcd = bid & 7, r = bid >> 3;
      bn = (MODE == 0) ? xcd * 3 + (r >> 5) : xcd * 2 + (r >> 5);
      bm = r & 31; }
    const int t = threadIdx.x, w = t >> 6, lane = t & 63;
    const int wr = w >> 1, wc = w & 1, lr = lane & 15, lg = lane >> 4;
    f32x4 acc[4][NJ] = {};

    const int srow = w * 16 + (lane >> 2);
    const int schunk = lane & 3;
    const f16* Ab = A + (size_t)(bm * 128) * HD;
    const f16* Wb = W + (size_t)(bn * BN) * HD;
    f16* Asw = As + w * 512;
    f16* Bsw = Bs + w * 512;

#define GSTAGE(K0)                                                              \
    {                                                                           \
        _Pragma("unroll")                                                       \
        for (int i = 0; i < 2; i++) {                                           \
            int r = i * 64 + srow;                                              \
            int gc = ((schunk ^ ((r >> 1) & 3)) * 8);                           \
            gl_lds16(Ab + (size_t)r * HD + (K0) + gc, Asw + i * 2048);          \
        }                                                                       \
        if (MODE == 0) {                                                        \
            _Pragma("unroll")                                                   \
            for (int i = 0; i < 2; i++) {                                       \
                int r = i * 64 + srow;                                          \
                int gc = ((schunk ^ ((r >> 1) & 3)) * 8);                       \
                gl_lds16(Wb + (size_t)r * HD + (K0) + gc, Bsw + i * 2048);      \
            }                                                                   \
        } else {                                                                \
            int r = srow;                                                       \
            int gc = ((schunk ^ ((r >> 1) & 3)) * 8);                           \
            gl_lds16(Wb + (size_t)r * HD + (K0) + gc, Bsw);                     \
        }                                                                       \
    }

    GSTAGE(0)

    for (int k0 = 0;;) {
        __syncthreads();
        f16x8 af[4], bf[NJ];
        #pragma unroll
        for (int i = 0; i < 4; i++) {
            int ra = wr * 64 + i * 16 + lr;
            af[i] = *(const f16x8*)(As + ra * 32 + ((lg ^ ((ra >> 1) & 3)) * 8));
        }
        #pragma unroll
        for (int j = 0; j < NJ; j++) {
            int rb = wc * (BN / 2) + j * 16 + lr;
            bf[j] = *(const f16x8*)(Bs + rb * 32 + ((lg ^ ((rb >> 1) & 3)) * 8));
        }
        #pragma unroll
        for (int i = 0; i < 4; i++)
            #pragma unroll
            for (int j = 0; j < NJ; j++)
                acc[i][j] = __builtin_amdgcn_mfma_f32_16x16x32_f16(af[i], bf[j], acc[i][j], 0, 0, 0);
        k0 += 32;
        if (k0 >= HD) break;
        __syncthreads();
        GSTAGE(k0)
    }
#undef GSTAGE

    if (MODE == 0) {
        const int mat = bn >> 3;             // 0=Q 1=K 2=V
        const float* bp = mat == 0 ? b0 : mat == 1 ? b1 : b2;
        f16* base = oh + (size_t)mat * BH * MM * DH;
        #pragma unroll
        for (int i = 0; i < 4; i++) {
            #pragma unroll
            for (int j = 0; j < NJ; j++) {
                int n = bn * 128 + wc * 64 + j * 16 + lr;
                int nn = n & 1023, h = nn >> 6, dh = nn & 63;
                float bvv = bp[nn];
                int mg0 = bm * 128 + wr * 64 + i * 16 + lg * 4;
                int b = mg0 >> 11, mmr0 = mg0 & 2047;
                if (mat == 2) {
                    f16x4 o;
                    #pragma unroll
                    for (int r = 0; r < 4; r++) o[r] = (f16)(acc[i][j][r] + bvv);
                    *(f16x4*)(base + ((size_t)((b * NH + h) * DH + dh)) * MM + mmr0) = o;
                } else {
                    // Q pre-scaled by (1/8)*log2(e) so softmax uses raw v_exp_f32 (2^x)
                    float sc = (mat == 0) ? 0.1803368801111204f : 1.0f;
                    #pragma unroll
                    for (int r = 0; r < 4; r++)
                        base[((size_t)((b * NH + h) * MM + mmr0 + r)) * DH + dh] =
                            (f16)((acc[i][j][r] + bvv) * sc);
                }
            }
        }
    } else {
        #pragma unroll
        for (int i = 0; i < 4; i++)
            #pragma unroll
            for (int j = 0; j < NJ; j++) {
                int n = bn * 64 + wc * 32 + j * 16 + lr;
                float bvv = b0[n];
                #pragma unroll
                for (int r = 0; r < 4; r++) {
                    int mg = bm * 128 + wr * 64 + i * 16 + lg * 4 + r;
                    of[(size_t)mg * HD + n] = acc[i][j][r] + bvv;
                }
            }
    }
}

// ---------------- flash attention (R14-exact, session best 52.8 us): 8-wave, 3-buffer, 1 barrier -
__global__ __launch_bounds__(512, 4) void attn_kernel(const f16* __restrict__ Q,
                                                      const f16* __restrict__ K,
                                                      const f16* __restrict__ Vt,
                                                      f16* __restrict__ ctx) {
    __shared__ f16 Kl[3][64][64];   // 24 KB: [buf][kv][dh], 16B chunks XOR-swizzled by row&7
    __shared__ f16 Vl[3][64][64];   // 24 KB: [buf][dh][kv]
    __shared__ f16 Pl[8][32][32];   // 16 KB: per-wave P, granule-XOR by (row>>1)&3
    const int bid = blockIdx.x;                  // [0,512)
    const int xcd = bid & 7, idx = bid >> 3;     // idx in [0,64)
    const int bh = xcd * 4 + (idx >> 4);         // 4 heads per XCD
    const int qblk2 = idx & 15;                  // 128-row q block

    const int t = threadIdx.x, w = t >> 6, lane = t & 63;
    const int lr = lane & 15, lg = lane >> 4;
    const int wq = w >> 1, wkv = w & 1;          // 4 x 2 quadrant role
    const int q0B = qblk2 * 128 + wq * 32;
    const int kvb = wkv * 32;
    const int dtile = q0B >> 6;                  // KV tile containing this wave's diagonal
    const bool dwave = (wkv == (wq & 1));        // wave sees the diagonal in that tile

    const f16* Qb = Q + (size_t)bh * MM * DH;
    const f16* Kb = K + (size_t)bh * MM * DH;
    const f16* Vb = Vt + (size_t)bh * DH * MM;

    const int srowS = lane >> 3;                 // 0..7 staging row-in-8
    const int sxc = ((lane & 7) ^ srowS) * 8;    // inverse-swizzled source chunk (f16 units)
    const int lds_r = w * 8;                     // wave's staging row block (8 rows)

    f16x8 qfr[2][2];
    #pragma unroll
    for (int qf = 0; qf < 2; qf++)
        #pragma unroll
        for (int c = 0; c < 2; c++)
            qfr[qf][c] = *(const f16x8*)(Qb + (size_t)(q0B + qf * 16 + lr) * DH + c * 32 + lg * 8);

    f32x4 po[4][2] = {};                         // [df][qf]
    float lsum0 = 0.f, lsum1 = 0.f;
    const int sw = (lr & 7) * 8;
    const int ko0 = (lg * 8) ^ sw, ko1 = (32 + lg * 8) ^ sw;
    const int vko = (kvb + lg * 8) ^ sw;
    const int ps = (lr >> 1) & 3;
    f16* Pw = &Pl[w][0][0];
    const int pro = lr * 32 + ((lg ^ ps) * 8);

    // prologue: stage tiles 0,1 into bufs 0,1 (2 loads per wave per tile)
    #pragma unroll
    for (int tt = 0; tt < 2; tt++) {
        int row = lds_r + srowS;
        gl_lds16(Kb + (size_t)(tt * 64 + row) * DH + sxc, &Kl[tt][lds_r][0]);
        gl_lds16(Vb + (size_t)row * MM + tt * 64 + sxc, &Vl[tt][lds_r][0]);
    }

#define ATTN_BODY(CUR, NXT, IT, VMN)                                                         \
    {                                                                                        \
        const int it_ = (IT);                                                                \
        asm volatile("s_waitcnt vmcnt(" #VMN ")" ::: "memory");  /* tile IT staged (own) */  \
        __builtin_amdgcn_s_barrier();                            /* ...and all waves */      \
        if (it_ < 30) {   /* stage tile IT+2; barrier above proves NXT's readers done */     \
            const int jn = (it_ + 2) * 64;                                                   \
            int row = lds_r + srowS;                                                         \
            gl_lds16(Kb + (size_t)(jn + row) * DH + sxc, &Kl[NXT][lds_r][0]);                \
            gl_lds16(Vb + (size_t)row * MM + jn + sxc, &Vl[NXT][lds_r][0]);                  \
        }                                                                                    \
        f32x4 s00 = {}, s01 = {}, s10 = {}, s11 = {};   /* s{fq}{qf} */                      \
        __builtin_amdgcn_s_setprio(1);                                                       \
        {                                                                                    \
            const f16* kr0 = &Kl[CUR][kvb + lr][0];                                          \
            f16x8 ka = *(const f16x8*)(kr0 + ko0);                                           \
            f16x8 kb = *(const f16x8*)(kr0 + ko1);                                           \
            s00 = __builtin_amdgcn_mfma_f32_16x16x32_f16(ka, qfr[0][0], s00, 0, 0, 0);       \
            s00 = __builtin_amdgcn_mfma_f32_16x16x32_f16(kb, qfr[0][1], s00, 0, 0, 0);       \
            s01 = __builtin_amdgcn_mfma_f32_16x16x32_f16(ka, qfr[1][0], s01, 0, 0, 0);       \
            s01 = __builtin_amdgcn_mfma_f32_16x16x32_f16(kb, qfr[1][1], s01, 0, 0, 0);       \
            const f16* kr1 = &Kl[CUR][kvb + 16 + lr][0];                                     \
            f16x8 kc = *(const f16x8*)(kr1 + ko0);                                           \
            f16x8 kd = *(const f16x8*)(kr1 + ko1);                                           \
            s10 = __builtin_amdgcn_mfma_f32_16x16x32_f16(kc, qfr[0][0], s10, 0, 0, 0);       \
            s10 = __builtin_amdgcn_mfma_f32_16x16x32_f16(kd, qfr[0][1], s10, 0, 0, 0);       \
            s11 = __builtin_amdgcn_mfma_f32_16x16x32_f16(kc, qfr[1][0], s11, 0, 0, 0);       \
            s11 = __builtin_amdgcn_mfma_f32_16x16x32_f16(kd, qfr[1][1], s11, 0, 0, 0);       \
        }                                                                                    \
        __builtin_amdgcn_s_setprio(0);                                                       \
        if (it_ == dtile && dwave) {   /* multiplicative diag-zero: score 0 -> P = 1 */      \
            int rr = lr - lg * 4;                                                            \
            if (rr >= 0 && rr < 4) { s00[rr] = 0.f; s11[rr] = 0.f; }                         \
        }                                                                                    \
        _Pragma("unroll")                                                                    \
        for (int u = 0; u < 4; u++) {                                                        \
            const f32x4 sv = (u == 0) ? s00 : (u == 1) ? s01 : (u == 2) ? s10 : s11;         \
            const int fq = u >> 1, qf = u & 1;                                               \
            float p0 = fexp2(sv[0]), p1 = fexp2(sv[1]);                                      \
            float p2 = fexp2(sv[2]), p3 = fexp2(sv[3]);                                      \
            if (qf == 0) lsum0 += (p0 + p1) + (p2 + p3);                                     \
            else         lsum1 += (p0 + p1) + (p2 + p3);                                     \
            fp16x2 lo = __builtin_amdgcn_cvt_pkrtz(p0, p1);                                  \
            fp16x2 hi = __builtin_amdgcn_cvt_pkrtz(p2, p3);                                  \
            uint2 pr; pr.x = __builtin_bit_cast(uint32_t, lo);                               \
            pr.y = __builtin_bit_cast(uint32_t, hi);                                         \
            *(f16x4*)(Pw + (qf * 16 + lr) * 32 +                                             \
                      (((fq * 2 + (lg >> 1)) ^ ps) * 8) + (lg & 1) * 4) =                    \
                __builtin_bit_cast(f16x4, pr);                                               \
        }                                                                                    \
        asm volatile("s_waitcnt lgkmcnt(0)" ::: "memory");  /* wave-local P visibility */    \
        f16x8 pf0 = *(const f16x8*)(Pw + pro);                                               \
        f16x8 pf1 = *(const f16x8*)(Pw + 512 + pro);                                         \
        __builtin_amdgcn_s_setprio(1);                                                       \
        _Pragma("unroll")                                                                    \
        for (int df = 0; df < 4; df++) {                                                     \
            const f16* vr = &Vl[CUR][df * 16 + lr][0];                                       \
            f16x8 va = *(const f16x8*)(vr + vko);                                            \
            po[df][0] = __builtin_amdgcn_mfma_f32_16x16x32_f16(va, pf0, po[df][0], 0, 0, 0); \
            po[df][1] = __builtin_amdgcn_mfma_f32_16x16x32_f16(va, pf1, po[df][1], 0, 0, 0); \
        }                                                                                    \
        __builtin_amdgcn_s_setprio(0);                                                       \
    }

    for (int itp = 0; itp < 10; ++itp) {
        ATTN_BODY(0, 2, 3 * itp,     2)
        ATTN_BODY(1, 0, 3 * itp + 1, 2)
        ATTN_BODY(2, 1, 3 * itp + 2, 2)
    }
    ATTN_BODY(0, 2, 30, 2)
    ATTN_BODY(1, 0, 31, 0)
#undef ATTN_BODY

    // ---- epilogue: sum lg-groups in-wave, then combine kv-halves (wave pairs w, w^1) ----
    lsum0 += __shfl_xor(lsum0, 16); lsum0 += __shfl_xor(lsum0, 32);
    lsum1 += __shfl_xor(lsum1, 16); lsum1 += __shfl_xor(lsum1, 32);
    __syncthreads();                             // Kl/Vl/Pl free for reuse
    float* shf0 = (float*)(&Kl[0][0][0]);        // qf=0 exchange: 256 rows x stride 17 f32
    float* shf1 = (float*)(&Vl[0][0][0]);        // qf=1 exchange
    float* shl  = (float*)(&Pl[0][0][0]);        // lsum exchange: 256 x 2 f32
    const int xi = wq * 64 + lane;               // [0,256)
    if (wkv == 1) {
        float* d0 = shf0 + (size_t)xi * 17;
        float* d1 = shf1 + (size_t)xi * 17;
        #pragma unroll
        for (int df = 0; df < 4; df++) {
            *(f32x4*)(d0 + df * 4) = po[df][0];
            *(f32x4*)(d1 + df * 4) = po[df][1];
        }
        shl[xi * 2]     = lsum0;
        shl[xi * 2 + 1] = lsum1;
    }
    __syncthreads();
    if (wkv == 0) {
        const float* s0 = shf0 + (size_t)xi * 17;
        const float* s1 = shf1 + (size_t)xi * 17;
        const float inv0 = 1.f / (lsum0 + shl[xi * 2]);
        const float inv1 = 1.f / (lsum1 + shl[xi * 2 + 1]);
        const int b = bh >> 4, hh = bh & 15;
        #pragma unroll
        for (int qf = 0; qf < 2; qf++) {
            const float inv = qf ? inv1 : inv0;
            const float* s = qf ? s1 : s0;
            f16* cp = ctx + ((size_t)(b * MM + q0B + qf * 16 + lr)) * HD + hh * DH;
            #pragma unroll
            for (int df = 0; df < 4; df++) {
                f16x4 o;
                #pragma unroll
                for (int r = 0; r < 4; r++)
                    o[r] = (f16)((po[df][qf][r] + s[df * 4 + r]) * inv);
                *(f16x4*)(cp + df * 16 + lg * 4) = o;
            }
        }
    }
}

extern "C" void kernel_launch(void* const* d_in, const int* in_sizes, int n_in,
                              void* d_out, int out_size, void* d_ws, size_t ws_size,
                              hipStream_t stream) {
    const float* x  = (const float*)d_in[0];
    const float* Wq = (const float*)d_in[1];
    const float* bq = (const float*)d_in[2];
    const float* Wk = (const float*)d_in[3];
    const float* bk = (const float*)d_in[4];
    const float* Wv = (const float*)d_in[5];
    const float* bv = (const float*)d_in[6];
    const float* Wo = (const float*)d_in[7];
    const float* bo = (const float*)d_in[8];
    float* out = (float*)d_out;

    f16* xh  = (f16*)d_ws;                       // 4096*1024
    f16* wqh = xh  + (size_t)MT * HD;            // 3x 1024*1024 contiguous (fused QKV weight)
    f16* woh = wqh + (size_t)3 * HD * HD;
    f16* Qh  = woh + (size_t)HD * HD;            // Qh|Kh|Vth contiguous
    f16* ctxh= Qh  + (size_t)3 * BH * MM * DH;

    const int total4 = MT * HD / 4 + HD * HD;
    cvt_all<<<(total4 + 255) / 256, 256, 0, stream>>>(x, Wq, Wk, Wv, Wo, xh);

    gemm_m97<0><<<768, 256, 0, stream>>>(xh, wqh, bq, bk, bv, Qh, nullptr);

    attn_kernel<<<512, 512, 0, stream>>>(Qh, Qh + (size_t)BH * MM * DH,
                                         Qh + (size_t)2 * BH * MM * DH, ctxh);

    gemm_m97<1><<<512, 256, 0, stream>>>(ctxh, woh, bo, nullptr, nullptr, nullptr, out);
}

// Round 21
// 109.979 us; speedup vs baseline: 1.3497x; 1.0484x over previous
//
#include <hip/hip_runtime.h>
#include <stdint.h>

typedef _Float16 f16;
typedef __attribute__((ext_vector_type(8))) _Float16 f16x8;
typedef __attribute__((ext_vector_type(4))) _Float16 f16x4;
typedef __attribute__((ext_vector_type(2))) __fp16 fp16x2;
typedef __attribute__((ext_vector_type(4))) float f32x4;

#define HD 1024
#define NH 16
#define DH 64
#define BB 2
#define MM 2048
#define BH (BB*NH)          // 32
#define MT (BB*MM)          // 4096 total rows

__device__ __forceinline__ void gl_lds16(const f16* g, f16* l) {
    __builtin_amdgcn_global_load_lds((const __attribute__((address_space(1))) uint32_t*)g,
                                     (__attribute__((address_space(3))) uint32_t*)l, 16, 0, 0);
}

__device__ __forceinline__ float fexp2(float x) {
    float r; asm("v_exp_f32 %0, %1" : "=v"(r) : "v"(x)); return r;
}

// ---------------- fused fp32 -> fp16 conversion (x + 4 weights, contiguous dst) ----------------
__global__ void cvt_all(const float* __restrict__ x,  const float* __restrict__ wq,
                        const float* __restrict__ wk, const float* __restrict__ wv,
                        const float* __restrict__ wo, f16* __restrict__ dst) {
    const int XN4 = MT * HD / 4;          // 1048576
    const int WN4 = HD * HD / 4;          // 262144 = 2^18
    int i = blockIdx.x * blockDim.x + threadIdx.x;
    if (i >= XN4 + 4 * WN4) return;
    const float* s; int off;
    if (i < XN4) { s = x; off = i; }
    else {
        int k = i - XN4, wsel = k >> 18;
        off = k & (WN4 - 1);
        s = wsel == 0 ? wq : wsel == 1 ? wk : wsel == 2 ? wv : wo;
    }
    float4 v = ((const float4*)s)[off];
    f16x4 h;
    h[0] = (f16)v.x; h[1] = (f16)v.y; h[2] = (f16)v.z; h[3] = (f16)v.w;
    ((f16x4*)dst)[i] = h;
}

// ---------------- m97-style GEMM, BK=64 (half the barriers of BK=32) ----------------------------
// MODE 0: fused QKV, 128x128 tile, grid=768. W = [3072][1024]. Q scaled by (1/8)*log2(e); V^T out.
// MODE 1: out proj, 128x64 tile, grid=512. fp32 out = acc + b0.
// LDS rows are 8x16B granules; staging writes granule (l&7) of row (l>>3) from global chunk
// ((l&7)^(l>>3)) -> LDS[row][g] = global[row][g ^ (row&7)]; frag reads XOR the same term (2-way
// bank aliasing only = free). Two K=32 sub-steps per barrier pair keep the live-register window
// identical to BK=32 (no R17/R19-style spill).
template<int MODE>
__global__ __launch_bounds__(256, 3) void gemm_m97(const f16* __restrict__ A,
                                                   const f16* __restrict__ W,
                                                   const float* __restrict__ b0,
                                                   const float* __restrict__ b1,
                                                   const float* __restrict__ b2,
                                                   f16* __restrict__ oh,
                                                   float* __restrict__ of) {
    constexpr int BN = (MODE == 0) ? 128 : 64;   // tile N
    constexpr int NJ = BN / 32;                  // bf frags per wave (4 or 2)
    __shared__ f16 As[128 * 64];                 // 16 KB
    __shared__ f16 Bs[BN * 64];                  // 16 / 8 KB
    const int bid = blockIdx.x;
    int bn, bm;
    { int xcd = bid & 7, r = bid >> 3;
      bn = (MODE == 0) ? xcd * 3 + (r >> 5) : xcd * 2 + (r >> 5);
      bm = r & 31; }
    const int t = threadIdx.x, w = t >> 6, lane = t & 63;
    const int wr = w >> 1, wc = w & 1, lr = lane & 15, lg = lane >> 4;
    f32x4 acc[4][NJ] = {};

    const int srow8 = lane >> 3;                 // 0..7
    const int sxc = ((lane & 7) ^ srow8) * 8;    // inverse-swizzled source chunk (f16 units)
    const f16* Ab = A + (size_t)(bm * 128) * HD;
    const f16* Wb = W + (size_t)(bn * BN) * HD;

#define GSTAGE(K0)                                                              \
    {                                                                           \
        _Pragma("unroll")                                                       \
        for (int i = 0; i < 4; i++) {            /* A: wave covers 32 rows */   \
            int r = w * 32 + i * 8 + srow8;                                     \
            gl_lds16(Ab + (size_t)r * HD + (K0) + sxc, As + (w * 32 + i * 8) * 64); \
        }                                                                       \
        if (MODE == 0) {                                                        \
            _Pragma("unroll")                                                   \
            for (int i = 0; i < 4; i++) {                                       \
                int r = w * 32 + i * 8 + srow8;                                 \
                gl_lds16(Wb + (size_t)r * HD + (K0) + sxc, Bs + (w * 32 + i * 8) * 64); \
            }                                                                   \
        } else {                                                                \
            _Pragma("unroll")                                                   \
            for (int i = 0; i < 2; i++) {        /* B: 64 rows total */         \
                int r = w * 16 + i * 8 + srow8;                                 \
                gl_lds16(Wb + (size_t)r * HD + (K0) + sxc, Bs + (w * 16 + i * 8) * 64); \
            }                                                                   \
        }                                                                       \
    }

    GSTAGE(0)

    for (int k0 = 0;;) {
        __syncthreads();
        #pragma unroll
        for (int kc = 0; kc < 2; kc++) {
            f16x8 af[4], bf[NJ];
            #pragma unroll
            for (int i = 0; i < 4; i++) {
                int ra = wr * 64 + i * 16 + lr;
                af[i] = *(const f16x8*)(As + ra * 64 + (((kc * 4 + lg) ^ (ra & 7)) * 8));
            }
            #pragma unroll
            for (int j = 0; j < NJ; j++) {
                int rb = wc * (BN / 2) + j * 16 + lr;
                bf[j] = *(const f16x8*)(Bs + rb * 64 + (((kc * 4 + lg) ^ (rb & 7)) * 8));
            }
            #pragma unroll
            for (int i = 0; i < 4; i++)
                #pragma unroll
                for (int j = 0; j < NJ; j++)
                    acc[i][j] = __builtin_amdgcn_mfma_f32_16x16x32_f16(af[i], bf[j], acc[i][j], 0, 0, 0);
        }
        k0 += 64;
        if (k0 >= HD) break;
        __syncthreads();
        GSTAGE(k0)
    }
#undef GSTAGE

    if (MODE == 0) {
        const int mat = bn >> 3;             // 0=Q 1=K 2=V
        const float* bp = mat == 0 ? b0 : mat == 1 ? b1 : b2;
        f16* base = oh + (size_t)mat * BH * MM * DH;
        #pragma unroll
        for (int i = 0; i < 4; i++) {
            #pragma unroll
            for (int j = 0; j < NJ; j++) {
                int n = bn * 128 + wc * 64 + j * 16 + lr;
                int nn = n & 1023, h = nn >> 6, dh = nn & 63;
                float bvv = bp[nn];
                int mg0 = bm * 128 + wr * 64 + i * 16 + lg * 4;
                int b = mg0 >> 11, mmr0 = mg0 & 2047;
                if (mat == 2) {
                    f16x4 o;
                    #pragma unroll
                    for (int r = 0; r < 4; r++) o[r] = (f16)(acc[i][j][r] + bvv);
                    *(f16x4*)(base + ((size_t)((b * NH + h) * DH + dh)) * MM + mmr0) = o;
                } else {
                    // Q pre-scaled by (1/8)*log2(e) so softmax uses raw v_exp_f32 (2^x)
                    float sc = (mat == 0) ? 0.1803368801111204f : 1.0f;
                    #pragma unroll
                    for (int r = 0; r < 4; r++)
                        base[((size_t)((b * NH + h) * MM + mmr0 + r)) * DH + dh] =
                            (f16)((acc[i][j][r] + bvv) * sc);
                }
            }
        }
    } else {
        #pragma unroll
        for (int i = 0; i < 4; i++)
            #pragma unroll
            for (int j = 0; j < NJ; j++) {
                int n = bn * 64 + wc * 32 + j * 16 + lr;
                float bvv = b0[n];
                #pragma unroll
                for (int r = 0; r < 4; r++) {
                    int mg = bm * 128 + wr * 64 + i * 16 + lg * 4 + r;
                    of[(size_t)mg * HD + n] = acc[i][j][r] + bvv;
                }
            }
    }
}

// ---------------- flash attention (R14-exact, session best 52.8 us): 8-wave, 3-buffer, 1 barrier -
__global__ __launch_bounds__(512, 4) void attn_kernel(const f16* __restrict__ Q,
                                                      const f16* __restrict__ K,
                                                      const f16* __restrict__ Vt,
                                                      f16* __restrict__ ctx) {
    __shared__ f16 Kl[3][64][64];   // 24 KB: [buf][kv][dh], 16B chunks XOR-swizzled by row&7
    __shared__ f16 Vl[3][64][64];   // 24 KB: [buf][dh][kv]
    __shared__ f16 Pl[8][32][32];   // 16 KB: per-wave P, granule-XOR by (row>>1)&3
    const int bid = blockIdx.x;                  // [0,512)
    const int xcd = bid & 7, idx = bid >> 3;     // idx in [0,64)
    const int bh = xcd * 4 + (idx >> 4);         // 4 heads per XCD
    const int qblk2 = idx & 15;                  // 128-row q block

    const int t = threadIdx.x, w = t >> 6, lane = t & 63;
    const int lr = lane & 15, lg = lane >> 4;
    const int wq = w >> 1, wkv = w & 1;          // 4 x 2 quadrant role
    const int q0B = qblk2 * 128 + wq * 32;
    const int kvb = wkv * 32;
    const int dtile = q0B >> 6;                  // KV tile containing this wave's diagonal
    const bool dwave = (wkv == (wq & 1));        // wave sees the diagonal in that tile

    const f16* Qb = Q + (size_t)bh * MM * DH;
    const f16* Kb = K + (size_t)bh * MM * DH;
    const f16* Vb = Vt + (size_t)bh * DH * MM;

    const int srowS = lane >> 3;                 // 0..7 staging row-in-8
    const int sxc = ((lane & 7) ^ srowS) * 8;    // inverse-swizzled source chunk (f16 units)
    const int lds_r = w * 8;                     // wave's staging row block (8 rows)

    f16x8 qfr[2][2];
    #pragma unroll
    for (int qf = 0; qf < 2; qf++)
        #pragma unroll
        for (int c = 0; c < 2; c++)
            qfr[qf][c] = *(const f16x8*)(Qb + (size_t)(q0B + qf * 16 + lr) * DH + c * 32 + lg * 8);

    f32x4 po[4][2] = {};                         // [df][qf]
    float lsum0 = 0.f, lsum1 = 0.f;
    const int sw = (lr & 7) * 8;
    const int ko0 = (lg * 8) ^ sw, ko1 = (32 + lg * 8) ^ sw;
    const int vko = (kvb + lg * 8) ^ sw;
    const int ps = (lr >> 1) & 3;
    f16* Pw = &Pl[w][0][0];
    const int pro = lr * 32 + ((lg ^ ps) * 8);

    // prologue: stage tiles 0,1 into bufs 0,1 (2 loads per wave per tile)
    #pragma unroll
    for (int tt = 0; tt < 2; tt++) {
        int row = lds_r + srowS;
        gl_lds16(Kb + (size_t)(tt * 64 + row) * DH + sxc, &Kl[tt][lds_r][0]);
        gl_lds16(Vb + (size_t)row * MM + tt * 64 + sxc, &Vl[tt][lds_r][0]);
    }

#define ATTN_BODY(CUR, NXT, IT, VMN)                                                         \
    {                                                                                        \
        const int it_ = (IT);                                                                \
        asm volatile("s_waitcnt vmcnt(" #VMN ")" ::: "memory");  /* tile IT staged (own) */  \
        __builtin_amdgcn_s_barrier();                            /* ...and all waves */      \
        if (it_ < 30) {   /* stage tile IT+2; barrier above proves NXT's readers done */     \
            const int jn = (it_ + 2) * 64;                                                   \
            int row = lds_r + srowS;                                                         \
            gl_lds16(Kb + (size_t)(jn + row) * DH + sxc, &Kl[NXT][lds_r][0]);                \
            gl_lds16(Vb + (size_t)row * MM + jn + sxc, &Vl[NXT][lds_r][0]);                  \
        }                                                                                    \
        f32x4 s00 = {}, s01 = {}, s10 = {}, s11 = {};   /* s{fq}{qf} */                      \
        __builtin_amdgcn_s_setprio(1);                                                       \
        {                                                                                    \
            const f16* kr0 = &Kl[CUR][kvb + lr][0];                                          \
            f16x8 ka = *(const f16x8*)(kr0 + ko0);                                           \
            f16x8 kb = *(const f16x8*)(kr0 + ko1);                                           \
            s00 = __builtin_amdgcn_mfma_f32_16x16x32_f16(ka, qfr[0][0], s00, 0, 0, 0);       \
            s00 = __builtin_amdgcn_mfma_f32_16x16x32_f16(kb, qfr[0][1], s00, 0, 0, 0);       \
            s01 = __builtin_amdgcn_mfma_f32_16x16x32_f16(ka, qfr[1][0], s01, 0, 0, 0);       \
            s01 = __builtin_amdgcn_mfma_f32_16x16x32_f16(kb, qfr[1][1], s01, 0, 0, 0);       \
            const f16* kr1 = &Kl[CUR][kvb + 16 + lr][0];                                     \
            f16x8 kc = *(const f16x8*)(kr1 + ko0);                                           \
            f16x8 kd = *(const f16x8*)(kr1 + ko1);                                           \
            s10 = __builtin_amdgcn_mfma_f32_16x16x32_f16(kc, qfr[0][0], s10, 0, 0, 0);       \
            s10 = __builtin_amdgcn_mfma_f32_16x16x32_f16(kd, qfr[0][1], s10, 0, 0, 0);       \
            s11 = __builtin_amdgcn_mfma_f32_16x16x32_f16(kc, qfr[1][0], s11, 0, 0, 0);       \
            s11 = __builtin_amdgcn_mfma_f32_16x16x32_f16(kd, qfr[1][1], s11, 0, 0, 0);       \
        }                                                                                    \
        __builtin_amdgcn_s_setprio(0);                                                       \
        if (it_ == dtile && dwave) {   /* multiplicative diag-zero: score 0 -> P = 1 */      \
            int rr = lr - lg * 4;                                                            \
            if (rr >= 0 && rr < 4) { s00[rr] = 0.f; s11[rr] = 0.f; }                         \
        }                                                                                    \
        _Pragma("unroll")                                                                    \
        for (int u = 0; u < 4; u++) {                                                        \
            const f32x4 sv = (u == 0) ? s00 : (u == 1) ? s01 : (u == 2) ? s10 : s11;         \
            const int fq = u >> 1, qf = u & 1;                                               \
            float p0 = fexp2(sv[0]), p1 = fexp2(sv[1]);                                      \
            float p2 = fexp2(sv[2]), p3 = fexp2(sv[3]);                                      \
            if (qf == 0) lsum0 += (p0 + p1) + (p2 + p3);                                     \
            else         lsum1 += (p0 + p1) + (p2 + p3);                                     \
            fp16x2 lo = __builtin_amdgcn_cvt_pkrtz(p0, p1);                                  \
            fp16x2 hi = __builtin_amdgcn_cvt_pkrtz(p2, p3);                                  \
            uint2 pr; pr.x = __builtin_bit_cast(uint32_t, lo);                               \
            pr.y = __builtin_bit_cast(uint32_t, hi);                                         \
            *(f16x4*)(Pw + (qf * 16 + lr) * 32 +                                             \
                      (((fq * 2 + (lg >> 1)) ^ ps) * 8) + (lg & 1) * 4) =                    \
                __builtin_bit_cast(f16x4, pr);                                               \
        }                                                                                    \
        asm volatile("s_waitcnt lgkmcnt(0)" ::: "memory");  /* wave-local P visibility */    \
        f16x8 pf0 = *(const f16x8*)(Pw + pro);                                               \
        f16x8 pf1 = *(const f16x8*)(Pw + 512 + pro);                                         \
        __builtin_amdgcn_s_setprio(1);                                                       \
        _Pragma("unroll")                                                                    \
        for (int df = 0; df < 4; df++) {                                                     \
            const f16* vr = &Vl[CUR][df * 16 + lr][0];                                       \
            f16x8 va = *(const f16x8*)(vr + vko);                                            \
            po[df][0] = __builtin_amdgcn_mfma_f32_16x16x32_f16(va, pf0, po[df][0], 0, 0, 0); \
            po[df][1] = __builtin_amdgcn_mfma_f32_16x16x32_f16(va, pf1, po[df][1], 0, 0, 0); \
        }                                                                                    \
        __builtin_amdgcn_s_setprio(0);                                                       \
    }

    for (int itp = 0; itp < 10; ++itp) {
        ATTN_BODY(0, 2, 3 * itp,     2)
        ATTN_BODY(1, 0, 3 * itp + 1, 2)
        ATTN_BODY(2, 1, 3 * itp + 2, 2)
    }
    ATTN_BODY(0, 2, 30, 2)
    ATTN_BODY(1, 0, 31, 0)
#undef ATTN_BODY

    // ---- epilogue: sum lg-groups in-wave, then combine kv-halves (wave pairs w, w^1) ----
    lsum0 += __shfl_xor(lsum0, 16); lsum0 += __shfl_xor(lsum0, 32);
    lsum1 += __shfl_xor(lsum1, 16); lsum1 += __shfl_xor(lsum1, 32);
    __syncthreads();                             // Kl/Vl/Pl free for reuse
    float* shf0 = (float*)(&Kl[0][0][0]);        // qf=0 exchange: 256 rows x stride 17 f32
    float* shf1 = (float*)(&Vl[0][0][0]);        // qf=1 exchange
    float* shl  = (float*)(&Pl[0][0][0]);        // lsum exchange: 256 x 2 f32
    const int xi = wq * 64 + lane;               // [0,256)
    if (wkv == 1) {
        float* d0 = shf0 + (size_t)xi * 17;
        float* d1 = shf1 + (size_t)xi * 17;
        #pragma unroll
        for (int df = 0; df < 4; df++) {
            *(f32x4*)(d0 + df * 4) = po[df][0];
            *(f32x4*)(d1 + df * 4) = po[df][1];
        }
        shl[xi * 2]     = lsum0;
        shl[xi * 2 + 1] = lsum1;
    }
    __syncthreads();
    if (wkv == 0) {
        const float* s0 = shf0 + (size_t)xi * 17;
        const float* s1 = shf1 + (size_t)xi * 17;
        const float inv0 = 1.f / (lsum0 + shl[xi * 2]);
        const float inv1 = 1.f / (lsum1 + shl[xi * 2 + 1]);
        const int b = bh >> 4, hh = bh & 15;
        #pragma unroll
        for (int qf = 0; qf < 2; qf++) {
            const float inv = qf ? inv1 : inv0;
            const float* s = qf ? s1 : s0;
            f16* cp = ctx + ((size_t)(b * MM + q0B + qf * 16 + lr)) * HD + hh * DH;
            #pragma unroll
            for (int df = 0; df < 4; df++) {
                f16x4 o;
                #pragma unroll
                for (int r = 0; r < 4; r++)
                    o[r] = (f16)((po[df][qf][r] + s[df * 4 + r]) * inv);
                *(f16x4*)(cp + df * 16 + lg * 4) = o;
            }
        }
    }
}

extern "C" void kernel_launch(void* const* d_in, const int* in_sizes, int n_in,
                              void* d_out, int out_size, void* d_ws, size_t ws_size,
                              hipStream_t stream) {
    const float* x  = (const float*)d_in[0];
    const float* Wq = (const float*)d_in[1];
    const float* bq = (const float*)d_in[2];
    const float* Wk = (const float*)d_in[3];
    const float* bk = (const float*)d_in[4];
    const float* Wv = (const float*)d_in[5];
    const float* bv = (const float*)d_in[6];
    const float* Wo = (const float*)d_in[7];
    const float* bo = (const float*)d_in[8];
    float* out = (float*)d_out;

    f16* xh  = (f16*)d_ws;                       // 4096*1024
    f16* wqh = xh  + (size_t)MT * HD;            // 3x 1024*1024 contiguous (fused QKV weight)
    f16* woh = wqh + (size_t)3 * HD * HD;
    f16* Qh  = woh + (size_t)HD * HD;            // Qh|Kh|Vth contiguous
    f16* ctxh= Qh  + (size_t)3 * BH * MM * DH;

    const int total4 = MT * HD / 4 + HD * HD;
    cvt_all<<<(total4 + 255) / 256, 256, 0, stream>>>(x, Wq, Wk, Wv, Wo, xh);

    gemm_m97<0><<<768, 256, 0, stream>>>(xh, wqh, bq, bk, bv, Qh, nullptr);

    attn_kernel<<<512, 512, 0, stream>>>(Qh, Qh + (size_t)BH * MM * DH,
                                         Qh + (size_t)2 * BH * MM * DH, ctxh);

    gemm_m97<1><<<512, 256, 0, stream>>>(ctxh, woh, bo, nullptr, nullptr, nullptr, out);
}

// Round 22
// 109.444 us; speedup vs baseline: 1.3563x; 1.0049x over previous
//
#include <hip/hip_runtime.h>
#include <stdint.h>

typedef _Float16 f16;
typedef __attribute__((ext_vector_type(8))) _Float16 f16x8;
typedef __attribute__((ext_vector_type(4))) _Float16 f16x4;
typedef __attribute__((ext_vector_type(2))) __fp16 fp16x2;
typedef __attribute__((ext_vector_type(4))) float f32x4;

#define HD 1024
#define NH 16
#define DH 64
#define BB 2
#define MM 2048
#define BH (BB*NH)          // 32
#define MT (BB*MM)          // 4096 total rows

__device__ __forceinline__ void gl_lds16(const f16* g, f16* l) {
    __builtin_amdgcn_global_load_lds((const __attribute__((address_space(1))) uint32_t*)g,
                                     (__attribute__((address_space(3))) uint32_t*)l, 16, 0, 0);
}

__device__ __forceinline__ float fexp2(float x) {
    float r; asm("v_exp_f32 %0, %1" : "=v"(r) : "v"(x)); return r;
}

// ---------------- fused fp32 -> fp16 conversion (x + 4 weights, contiguous dst) ----------------
__global__ void cvt_all(const float* __restrict__ x,  const float* __restrict__ wq,
                        const float* __restrict__ wk, const float* __restrict__ wv,
                        const float* __restrict__ wo, f16* __restrict__ dst) {
    const int XN4 = MT * HD / 4;          // 1048576
    const int WN4 = HD * HD / 4;          // 262144 = 2^18
    int i = blockIdx.x * blockDim.x + threadIdx.x;
    if (i >= XN4 + 4 * WN4) return;
    const float* s; int off;
    if (i < XN4) { s = x; off = i; }
    else {
        int k = i - XN4, wsel = k >> 18;
        off = k & (WN4 - 1);
        s = wsel == 0 ? wq : wsel == 1 ? wk : wsel == 2 ? wv : wo;
    }
    float4 v = ((const float4*)s)[off];
    f16x4 h;
    h[0] = (f16)v.x; h[1] = (f16)v.y; h[2] = (f16)v.z; h[3] = (f16)v.w;
    ((f16x4*)dst)[i] = h;
}

// ---------------- m97-style GEMM, BK=64 (R21 winner, unchanged) ---------------------------------
// MODE 0: fused QKV, 128x128 tile, grid=768. W = [3072][1024]. Q scaled by (1/8)*log2(e); V^T out.
// MODE 1: out proj, 128x64 tile, grid=512. fp32 out = acc + b0.
template<int MODE>
__global__ __launch_bounds__(256, 3) void gemm_m97(const f16* __restrict__ A,
                                                   const f16* __restrict__ W,
                                                   const float* __restrict__ b0,
                                                   const float* __restrict__ b1,
                                                   const float* __restrict__ b2,
                                                   f16* __restrict__ oh,
                                                   float* __restrict__ of) {
    constexpr int BN = (MODE == 0) ? 128 : 64;   // tile N
    constexpr int NJ = BN / 32;                  // bf frags per wave (4 or 2)
    __shared__ f16 As[128 * 64];                 // 16 KB
    __shared__ f16 Bs[BN * 64];                  // 16 / 8 KB
    const int bid = blockIdx.x;
    int bn, bm;
    { int xcd = bid & 7, r = bid >> 3;
      bn = (MODE == 0) ? xcd * 3 + (r >> 5) : xcd * 2 + (r >> 5);
      bm = r & 31; }
    const int t = threadIdx.x, w = t >> 6, lane = t & 63;
    const int wr = w >> 1, wc = w & 1, lr = lane & 15, lg = lane >> 4;
    f32x4 acc[4][NJ] = {};

    const int srow8 = lane >> 3;                 // 0..7
    const int sxc = ((lane & 7) ^ srow8) * 8;    // inverse-swizzled source chunk (f16 units)
    const f16* Ab = A + (size_t)(bm * 128) * HD;
    const f16* Wb = W + (size_t)(bn * BN) * HD;

#define GSTAGE(K0)                                                              \
    {                                                                           \
        _Pragma("unroll")                                                       \
        for (int i = 0; i < 4; i++) {            /* A: wave covers 32 rows */   \
            int r = w * 32 + i * 8 + srow8;                                     \
            gl_lds16(Ab + (size_t)r * HD + (K0) + sxc, As + (w * 32 + i * 8) * 64); \
        }                                                                       \
        if (MODE == 0) {                                                        \
            _Pragma("unroll")                                                   \
            for (int i = 0; i < 4; i++) {                                       \
                int r = w * 32 + i * 8 + srow8;                                 \
                gl_lds16(Wb + (size_t)r * HD + (K0) + sxc, Bs + (w * 32 + i * 8) * 64); \
            }                                                                   \
        } else {                                                                \
            _Pragma("unroll")                                                   \
            for (int i = 0; i < 2; i++) {        /* B: 64 rows total */         \
                int r = w * 16 + i * 8 + srow8;                                 \
                gl_lds16(Wb + (size_t)r * HD + (K0) + sxc, Bs + (w * 16 + i * 8) * 64); \
            }                                                                   \
        }                                                                       \
    }

    GSTAGE(0)

    for (int k0 = 0;;) {
        __syncthreads();
        #pragma unroll
        for (int kc = 0; kc < 2; kc++) {
            f16x8 af[4], bf[NJ];
            #pragma unroll
            for (int i = 0; i < 4; i++) {
                int ra = wr * 64 + i * 16 + lr;
                af[i] = *(const f16x8*)(As + ra * 64 + (((kc * 4 + lg) ^ (ra & 7)) * 8));
            }
            #pragma unroll
            for (int j = 0; j < NJ; j++) {
                int rb = wc * (BN / 2) + j * 16 + lr;
                bf[j] = *(const f16x8*)(Bs + rb * 64 + (((kc * 4 + lg) ^ (rb & 7)) * 8));
            }
            #pragma unroll
            for (int i = 0; i < 4; i++)
                #pragma unroll
                for (int j = 0; j < NJ; j++)
                    acc[i][j] = __builtin_amdgcn_mfma_f32_16x16x32_f16(af[i], bf[j], acc[i][j], 0, 0, 0);
        }
        k0 += 64;
        if (k0 >= HD) break;
        __syncthreads();
        GSTAGE(k0)
    }
#undef GSTAGE

    if (MODE == 0) {
        const int mat = bn >> 3;             // 0=Q 1=K 2=V
        const float* bp = mat == 0 ? b0 : mat == 1 ? b1 : b2;
        f16* base = oh + (size_t)mat * BH * MM * DH;
        #pragma unroll
        for (int i = 0; i < 4; i++) {
            #pragma unroll
            for (int j = 0; j < NJ; j++) {
                int n = bn * 128 + wc * 64 + j * 16 + lr;
                int nn = n & 1023, h = nn >> 6, dh = nn & 63;
                float bvv = bp[nn];
                int mg0 = bm * 128 + wr * 64 + i * 16 + lg * 4;
                int b = mg0 >> 11, mmr0 = mg0 & 2047;
                if (mat == 2) {
                    f16x4 o;
                    #pragma unroll
                    for (int r = 0; r < 4; r++) o[r] = (f16)(acc[i][j][r] + bvv);
                    *(f16x4*)(base + ((size_t)((b * NH + h) * DH + dh)) * MM + mmr0) = o;
                } else {
                    // Q pre-scaled by (1/8)*log2(e) so softmax uses raw v_exp_f32 (2^x)
                    float sc = (mat == 0) ? 0.1803368801111204f : 1.0f;
                    #pragma unroll
                    for (int r = 0; r < 4; r++)
                        base[((size_t)((b * NH + h) * MM + mmr0 + r)) * DH + dh] =
                            (f16)((acc[i][j][r] + bvv) * sc);
                }
            }
        }
    } else {
        #pragma unroll
        for (int i = 0; i < 4; i++)
            #pragma unroll
            for (int j = 0; j < NJ; j++) {
                int n = bn * 64 + wc * 32 + j * 16 + lr;
                float bvv = b0[n];
                #pragma unroll
                for (int r = 0; r < 4; r++) {
                    int mg = bm * 128 + wr * 64 + i * 16 + lg * 4 + r;
                    of[(size_t)mg * HD + n] = acc[i][j][r] + bvv;
                }
            }
    }
}

// ---------------- flash attention: R14 schedule + P rows padded to 40 f16 (80B, bank-rotating) ---
// 64B P rows put all 16 fragment rows on the same bank pair (XOR can only spread 4 ways -> the
// constant 2^21 conflict counter). 80B stride rotates rows by 20 banks (gcd 4 -> 8 positions);
// plain (un-XORed) addressing then lands 2-way on both b64 writes and b128 reads = free.
__global__ __launch_bounds__(512, 4) void attn_kernel(const f16* __restrict__ Q,
                                                      const f16* __restrict__ K,
                                                      const f16* __restrict__ Vt,
                                                      f16* __restrict__ ctx) {
    __shared__ f16 Kl[3][64][64];   // 24 KB: [buf][kv][dh], 16B chunks XOR-swizzled by row&7
    __shared__ f16 Vl[3][64][64];   // 24 KB: [buf][dh][kv]
    __shared__ f16 Pl[8][32][40];   // 20 KB: per-wave P, 80B rows (no XOR needed)
    const int bid = blockIdx.x;                  // [0,512)
    const int xcd = bid & 7, idx = bid >> 3;     // idx in [0,64)
    const int bh = xcd * 4 + (idx >> 4);         // 4 heads per XCD
    const int qblk2 = idx & 15;                  // 128-row q block

    const int t = threadIdx.x, w = t >> 6, lane = t & 63;
    const int lr = lane & 15, lg = lane >> 4;
    const int wq = w >> 1, wkv = w & 1;          // 4 x 2 quadrant role
    const int q0B = qblk2 * 128 + wq * 32;
    const int kvb = wkv * 32;
    const int dtile = q0B >> 6;                  // KV tile containing this wave's diagonal
    const bool dwave = (wkv == (wq & 1));        // wave sees the diagonal in that tile

    const f16* Qb = Q + (size_t)bh * MM * DH;
    const f16* Kb = K + (size_t)bh * MM * DH;
    const f16* Vb = Vt + (size_t)bh * DH * MM;

    const int srowS = lane >> 3;                 // 0..7 staging row-in-8
    const int sxc = ((lane & 7) ^ srowS) * 8;    // inverse-swizzled source chunk (f16 units)
    const int lds_r = w * 8;                     // wave's staging row block (8 rows)

    f16x8 qfr[2][2];
    #pragma unroll
    for (int qf = 0; qf < 2; qf++)
        #pragma unroll
        for (int c = 0; c < 2; c++)
            qfr[qf][c] = *(const f16x8*)(Qb + (size_t)(q0B + qf * 16 + lr) * DH + c * 32 + lg * 8);

    f32x4 po[4][2] = {};                         // [df][qf]
    float lsum0 = 0.f, lsum1 = 0.f;
    const int sw = (lr & 7) * 8;
    const int ko0 = (lg * 8) ^ sw, ko1 = (32 + lg * 8) ^ sw;
    const int vko = (kvb + lg * 8) ^ sw;
    f16* Pw = &Pl[w][0][0];
    const int pro = lr * 40 + lg * 8;            // b128-aligned: bytes 80*lr + 16*lg

    // prologue: stage tiles 0,1 into bufs 0,1 (2 loads per wave per tile)
    #pragma unroll
    for (int tt = 0; tt < 2; tt++) {
        int row = lds_r + srowS;
        gl_lds16(Kb + (size_t)(tt * 64 + row) * DH + sxc, &Kl[tt][lds_r][0]);
        gl_lds16(Vb + (size_t)row * MM + tt * 64 + sxc, &Vl[tt][lds_r][0]);
    }

#define ATTN_BODY(CUR, NXT, IT, VMN)                                                         \
    {                                                                                        \
        const int it_ = (IT);                                                                \
        asm volatile("s_waitcnt vmcnt(" #VMN ")" ::: "memory");  /* tile IT staged (own) */  \
        __builtin_amdgcn_s_barrier();                            /* ...and all waves */      \
        if (it_ < 30) {   /* stage tile IT+2; barrier above proves NXT's readers done */     \
            const int jn = (it_ + 2) * 64;                                                   \
            int row = lds_r + srowS;                                                         \
            gl_lds16(Kb + (size_t)(jn + row) * DH + sxc, &Kl[NXT][lds_r][0]);                \
            gl_lds16(Vb + (size_t)row * MM + jn + sxc, &Vl[NXT][lds_r][0]);                  \
        }                                                                                    \
        f32x4 s00 = {}, s01 = {}, s10 = {}, s11 = {};   /* s{fq}{qf} */                      \
        __builtin_amdgcn_s_setprio(1);                                                       \
        {                                                                                    \
            const f16* kr0 = &Kl[CUR][kvb + lr][0];                                          \
            f16x8 ka = *(const f16x8*)(kr0 + ko0);                                           \
            f16x8 kb = *(const f16x8*)(kr0 + ko1);                                           \
            s00 = __builtin_amdgcn_mfma_f32_16x16x32_f16(ka, qfr[0][0], s00, 0, 0, 0);       \
            s00 = __builtin_amdgcn_mfma_f32_16x16x32_f16(kb, qfr[0][1], s00, 0, 0, 0);       \
            s01 = __builtin_amdgcn_mfma_f32_16x16x32_f16(ka, qfr[1][0], s01, 0, 0, 0);       \
            s01 = __builtin_amdgcn_mfma_f32_16x16x32_f16(kb, qfr[1][1], s01, 0, 0, 0);       \
            const f16* kr1 = &Kl[CUR][kvb + 16 + lr][0];                                     \
            f16x8 kc = *(const f16x8*)(kr1 + ko0);                                           \
            f16x8 kd = *(const f16x8*)(kr1 + ko1);                                           \
            s10 = __builtin_amdgcn_mfma_f32_16x16x32_f16(kc, qfr[0][0], s10, 0, 0, 0);       \
            s10 = __builtin_amdgcn_mfma_f32_16x16x32_f16(kd, qfr[0][1], s10, 0, 0, 0);       \
            s11 = __builtin_amdgcn_mfma_f32_16x16x32_f16(kc, qfr[1][0], s11, 0, 0, 0);       \
            s11 = __builtin_amdgcn_mfma_f32_16x16x32_f16(kd, qfr[1][1], s11, 0, 0, 0);       \
        }                                                                                    \
        __builtin_amdgcn_s_setprio(0);                                                       \
        if (it_ == dtile && dwave) {   /* multiplicative diag-zero: score 0 -> P = 1 */      \
            int rr = lr - lg * 4;                                                            \
            if (rr >= 0 && rr < 4) { s00[rr] = 0.f; s11[rr] = 0.f; }                         \
        }                                                                                    \
        _Pragma("unroll")                                                                    \
        for (int u = 0; u < 4; u++) {                                                        \
            const f32x4 sv = (u == 0) ? s00 : (u == 1) ? s01 : (u == 2) ? s10 : s11;         \
            const int fq = u >> 1, qf = u & 1;                                               \
            float p0 = fexp2(sv[0]), p1 = fexp2(sv[1]);                                      \
            float p2 = fexp2(sv[2]), p3 = fexp2(sv[3]);                                      \
            if (qf == 0) lsum0 += (p0 + p1) + (p2 + p3);                                     \
            else         lsum1 += (p0 + p1) + (p2 + p3);                                     \
            fp16x2 lo = __builtin_amdgcn_cvt_pkrtz(p0, p1);                                  \
            fp16x2 hi = __builtin_amdgcn_cvt_pkrtz(p2, p3);                                  \
            uint2 pr; pr.x = __builtin_bit_cast(uint32_t, lo);                               \
            pr.y = __builtin_bit_cast(uint32_t, hi);                                         \
            *(f16x4*)(Pw + (qf * 16 + lr) * 40 + fq * 16 + lg * 4) =                         \
                __builtin_bit_cast(f16x4, pr);                                               \
        }                                                                                    \
        asm volatile("s_waitcnt lgkmcnt(0)" ::: "memory");  /* wave-local P visibility */    \
        f16x8 pf0 = *(const f16x8*)(Pw + pro);                                               \
        f16x8 pf1 = *(const f16x8*)(Pw + 640 + pro);        /* row 16+lr */                  \
        __builtin_amdgcn_s_setprio(1);                                                       \
        _Pragma("unroll")                                                                    \
        for (int df = 0; df < 4; df++) {                                                     \
            const f16* vr = &Vl[CUR][df * 16 + lr][0];                                       \
            f16x8 va = *(const f16x8*)(vr + vko);                                            \
            po[df][0] = __builtin_amdgcn_mfma_f32_16x16x32_f16(va, pf0, po[df][0], 0, 0, 0); \
            po[df][1] = __builtin_amdgcn_mfma_f32_16x16x32_f16(va, pf1, po[df][1], 0, 0, 0); \
        }                                                                                    \
        __builtin_amdgcn_s_setprio(0);                                                       \
    }

    for (int itp = 0; itp < 10; ++itp) {
        ATTN_BODY(0, 2, 3 * itp,     2)
        ATTN_BODY(1, 0, 3 * itp + 1, 2)
        ATTN_BODY(2, 1, 3 * itp + 2, 2)
    }
    ATTN_BODY(0, 2, 30, 2)
    ATTN_BODY(1, 0, 31, 0)
#undef ATTN_BODY

    // ---- epilogue: sum lg-groups in-wave, then combine kv-halves (wave pairs w, w^1) ----
    lsum0 += __shfl_xor(lsum0, 16); lsum0 += __shfl_xor(lsum0, 32);
    lsum1 += __shfl_xor(lsum1, 16); lsum1 += __shfl_xor(lsum1, 32);
    __syncthreads();                             // Kl/Vl/Pl free for reuse
    float* shf0 = (float*)(&Kl[0][0][0]);        // qf=0 exchange: 256 rows x stride 17 f32
    float* shf1 = (float*)(&Vl[0][0][0]);        // qf=1 exchange
    float* shl  = (float*)(&Pl[0][0][0]);        // lsum exchange: 256 x 2 f32
    const int xi = wq * 64 + lane;               // [0,256)
    if (wkv == 1) {
        float* d0 = shf0 + (size_t)xi * 17;
        float* d1 = shf1 + (size_t)xi * 17;
        #pragma unroll
        for (int df = 0; df < 4; df++) {
            *(f32x4*)(d0 + df * 4) = po[df][0];
            *(f32x4*)(d1 + df * 4) = po[df][1];
        }
        shl[xi * 2]     = lsum0;
        shl[xi * 2 + 1] = lsum1;
    }
    __syncthreads();
    if (wkv == 0) {
        const float* s0 = shf0 + (size_t)xi * 17;
        const float* s1 = shf1 + (size_t)xi * 17;
        const float inv0 = 1.f / (lsum0 + shl[xi * 2]);
        const float inv1 = 1.f / (lsum1 + shl[xi * 2 + 1]);
        const int b = bh >> 4, hh = bh & 15;
        #pragma unroll
        for (int qf = 0; qf < 2; qf++) {
            const float inv = qf ? inv1 : inv0;
            const float* s = qf ? s1 : s0;
            f16* cp = ctx + ((size_t)(b * MM + q0B + qf * 16 + lr)) * HD + hh * DH;
            #pragma unroll
            for (int df = 0; df < 4; df++) {
                f16x4 o;
                #pragma unroll
                for (int r = 0; r < 4; r++)
                    o[r] = (f16)((po[df][qf][r] + s[df * 4 + r]) * inv);
                *(f16x4*)(cp + df * 16 + lg * 4) = o;
            }
        }
    }
}

extern "C" void kernel_launch(void* const* d_in, const int* in_sizes, int n_in,
                              void* d_out, int out_size, void* d_ws, size_t ws_size,
                              hipStream_t stream) {
    const float* x  = (const float*)d_in[0];
    const float* Wq = (const float*)d_in[1];
    const float* bq = (const float*)d_in[2];
    const float* Wk = (const float*)d_in[3];
    const float* bk = (const float*)d_in[4];
    const float* Wv = (const float*)d_in[5];
    const float* bv = (const float*)d_in[6];
    const float* Wo = (const float*)d_in[7];
    const float* bo = (const float*)d_in[8];
    float* out = (float*)d_out;

    f16* xh  = (f16*)d_ws;                       // 4096*1024
    f16* wqh = xh  + (size_t)MT * HD;            // 3x 1024*1024 contiguous (fused QKV weight)
    f16* woh = wqh + (size_t)3 * HD * HD;
    f16* Qh  = woh + (size_t)HD * HD;            // Qh|Kh|Vth contiguous
    f16* ctxh= Qh  + (size_t)3 * BH * MM * DH;

    const int total4 = MT * HD / 4 + HD * HD;
    cvt_all<<<(total4 + 255) / 256, 256, 0, stream>>>(x, Wq, Wk, Wv, Wo, xh);

    gemm_m97<0><<<768, 256, 0, stream>>>(xh, wqh, bq, bk, bv, Qh, nullptr);

    attn_kernel<<<512, 512, 0, stream>>>(Qh, Qh + (size_t)BH * MM * DH,
                                         Qh + (size_t)2 * BH * MM * DH, ctxh);

    gemm_m97<1><<<512, 256, 0, stream>>>(ctxh, woh, bo, nullptr, nullptr, nullptr, out);
}